// Round 8
// baseline (440.277 us; speedup 1.0000x reference)
//
#include <hip/hip_runtime.h>
#include <hip/hip_cooperative_groups.h>

// ---------------------------------------------------------------------------
// PatternEncoder: 2x GCNConv -> global_mean_pool -> 5-layer MLP
// N=50000, E=800000, D=128, G=256, H=1024
// All GEMMs use MFMA bf16x3 (C = Ah@Bh + Ah@Bl + Al@Bh), rel err ~1e-5.
// Round 8: whole MLP fused into ONE cooperative kernel (64 blocks, grid.sync
// between layers) - removes 10 dispatches (split-K atomics, memsets, finish).
// ---------------------------------------------------------------------------

typedef __attribute__((ext_vector_type(8))) short bf16x8;
typedef __attribute__((ext_vector_type(8))) ushort u16x8;
typedef __attribute__((ext_vector_type(4))) float f32x4;

namespace cg = cooperative_groups;

__device__ __forceinline__ ushort f2bf(float f) {
    unsigned u = __float_as_uint(f);
    unsigned r = (u + 0x7FFFu + ((u >> 16) & 1u)) >> 16;
    return (ushort)r;
}
__device__ __forceinline__ float bf2f(ushort h) {
    return __uint_as_float(((unsigned)h) << 16);
}
__device__ __forceinline__ void gload16(const ushort* g, ushort* l) {
    __builtin_amdgcn_global_load_lds(
        (const __attribute__((address_space(1))) void*)g,
        (__attribute__((address_space(3))) void*)l, 16, 0, 0);
}

#define SWZ(r) (((r) >> 1) & 3)

// ------------------------------ CSR build ---------------------------------

__global__ void count_deg_kernel(const int* __restrict__ col, int E,
                                 int* __restrict__ indeg) {
    int i = blockIdx.x * blockDim.x + threadIdx.x;
    if (i < E) atomicAdd(&indeg[col[i]], 1);
}

__global__ void scan_p1_kernel(const int* __restrict__ indeg, int* __restrict__ bsum,
                               int N) {
    __shared__ int sm[256];
    int b = blockIdx.x, tid = threadIdx.x;
    int base = b * 1024 + tid * 4;
    int sum = 0;
    if (base + 4 <= N) {
        int4 v = *(const int4*)(indeg + base);
        sum = v.x + v.y + v.z + v.w;
    } else {
        for (int i = 0; i < 4; ++i) if (base + i < N) sum += indeg[base + i];
    }
    sm[tid] = sum;
    __syncthreads();
    for (int off = 128; off > 0; off >>= 1) {
        if (tid < off) sm[tid] += sm[tid + off];
        __syncthreads();
    }
    if (tid == 0) bsum[b] = sm[0];
}

__global__ void scan_p2_kernel(int* __restrict__ bsum, int nb) {
    __shared__ int sm[1024];
    int tid = threadIdx.x;
    int v = (tid < nb) ? bsum[tid] : 0;
    sm[tid] = v;
    __syncthreads();
    int val = v;
    for (int off = 1; off < 1024; off <<= 1) {
        int t = (tid >= off) ? sm[tid - off] : 0;
        __syncthreads();
        val += t;
        sm[tid] = val;
        __syncthreads();
    }
    if (tid < nb) bsum[tid] = val - v;
}

__global__ void scan_p3_kernel(const int* __restrict__ indeg, const int* __restrict__ bsum,
                               int* __restrict__ offs, float* __restrict__ dinv, int N) {
    __shared__ int sm[256];
    int b = blockIdx.x, tid = threadIdx.x;
    int base = b * 1024 + tid * 4;
    int d[4];
    int sum = 0;
    if (base + 4 <= N) {
        int4 v = *(const int4*)(indeg + base);
        d[0] = v.x; d[1] = v.y; d[2] = v.z; d[3] = v.w;
        sum = v.x + v.y + v.z + v.w;
    } else {
#pragma unroll
        for (int i = 0; i < 4; ++i) {
            d[i] = (base + i < N) ? indeg[base + i] : 0;
            sum += d[i];
        }
    }
    sm[tid] = sum;
    __syncthreads();
    int val = sum;
    for (int off = 1; off < 256; off <<= 1) {
        int t = (tid >= off) ? sm[tid - off] : 0;
        __syncthreads();
        val += t;
        sm[tid] = val;
        __syncthreads();
    }
    int prefix = bsum[b] + val - sum;
#pragma unroll
    for (int i = 0; i < 4; ++i) {
        int idx = base + i;
        if (idx < N) {
            offs[idx] = prefix;
            dinv[idx] = rsqrtf((float)(d[i] + 1));
            prefix += d[i];
            if (idx == N - 1) offs[N] = prefix;
        }
    }
}

__global__ void fill_adj_kernel(const int* __restrict__ row, const int* __restrict__ col,
                                int* __restrict__ cursor, int* __restrict__ adj, int E) {
    int e = blockIdx.x * blockDim.x + threadIdx.x;
    if (e < E) {
        int pos = atomicAdd(&cursor[col[e]], 1);
        adj[pos] = row[e];
    }
}

// ---------------- weight transpose+split (all 7 weights, one launch) --------
struct TJobs {
    const float* W[7];
    ushort* Th[7];
    ushort* Tl[7];
    int K[7];
    int Nn[7];
    int off[8];
};

__global__ __launch_bounds__(256) void tsplit_all_kernel(TJobs jobs) {
    __shared__ float sm[64][65];
    int b = blockIdx.x;
    int j = 0;
#pragma unroll
    for (int t = 1; t < 7; ++t) if (b >= jobs.off[t]) j = t;
    int local = b - jobs.off[j];
    int K = jobs.K[j], Nn = jobs.Nn[j];
    int kt = K >> 6;
    int k0 = (local % kt) * 64, n0 = (local / kt) * 64;
    const float* W = jobs.W[j];
    ushort* Th = jobs.Th[j];
    ushort* Tl = jobs.Tl[j];

    int tid = threadIdx.x;
    int r = tid >> 2, cq = tid & 3;
#pragma unroll
    for (int i = 0; i < 4; ++i) {
        float4 v = *(const float4*)(W + (size_t)(k0 + r) * Nn + n0 + cq * 16 + i * 4);
        sm[r][cq * 16 + i * 4 + 0] = v.x;
        sm[r][cq * 16 + i * 4 + 1] = v.y;
        sm[r][cq * 16 + i * 4 + 2] = v.z;
        sm[r][cq * 16 + i * 4 + 3] = v.w;
    }
    __syncthreads();
    int n = tid >> 2, kq = tid & 3;
    ushort h[16], l[16];
#pragma unroll
    for (int i = 0; i < 16; ++i) {
        float v = sm[kq * 16 + i][n];
        h[i] = f2bf(v);
        l[i] = f2bf(v - bf2f(h[i]));
    }
    size_t o = (size_t)(n0 + n) * K + k0 + kq * 16;
    *(u16x8*)(&Th[o]) = *(u16x8*)&h[0];
    *(u16x8*)(&Th[o + 8]) = *(u16x8*)&h[8];
    *(u16x8*)(&Tl[o]) = *(u16x8*)&l[0];
    *(u16x8*)(&Tl[o + 8]) = *(u16x8*)&l[8];
}

// ------------------------------ aggregation --------------------------------
// 2 nodes per wave: lanes 0-31 node A, lanes 32-63 node B; float4 per lane;
// 16-deep neighbor batching for memory-level parallelism.
template<int MODE>
__global__ void aggregate128_kernel(const float* __restrict__ hs,
                                    const int* __restrict__ offs,
                                    const int* __restrict__ adj,
                                    const float* __restrict__ dinv,
                                    const float* __restrict__ bias,
                                    float* __restrict__ outf,
                                    ushort* __restrict__ outh, ushort* __restrict__ outl,
                                    int N) {
    int wv = (blockIdx.x * blockDim.x + threadIdx.x) >> 6;
    int lane = threadIdx.x & 63;
    int half = lane >> 5, l32 = lane & 31;
    int node = wv * 2 + half;
    bool active = node < N;
    int nd = active ? node : N - 1;
    const float4* base = (const float4*)hs;
    float dself = dinv[nd];
    float4 a = base[(size_t)nd * 32 + l32];
    float ax, ay, az, aw;
    if (MODE == 1) { ax = a.x * dself; ay = a.y * dself; az = a.z * dself; aw = a.w * dself; }
    else           { ax = a.x;         ay = a.y;         az = a.z;         aw = a.w; }
    int s = offs[nd];
    int deg = active ? (offs[nd + 1] - s) : 0;
    int mx = max(deg, __shfl_xor(deg, 32));
    for (int j = 0; j < mx; j += 16) {
        int idx[16]; float wgt[16];
#pragma unroll
        for (int k = 0; k < 16; ++k) {
            int jj = j + k;
            bool valid = jj < deg;
            int ld = adj[s + (valid ? jj : 0)];
            idx[k] = valid ? ld : 0;
            wgt[k] = valid ? 1.f : 0.f;
        }
        float4 v[16];
#pragma unroll
        for (int k = 0; k < 16; ++k) v[k] = base[(size_t)idx[k] * 32 + l32];
        if (MODE == 1) {
#pragma unroll
            for (int k = 0; k < 16; ++k) wgt[k] *= dinv[idx[k]];
        }
#pragma unroll
        for (int k = 0; k < 16; ++k) {
            ax = fmaf(wgt[k], v[k].x, ax);
            ay = fmaf(wgt[k], v[k].y, ay);
            az = fmaf(wgt[k], v[k].z, az);
            aw = fmaf(wgt[k], v[k].w, aw);
        }
    }
    ax *= dself; ay *= dself; az *= dself; aw *= dself;
    if (!active) return;
    if (MODE == 0) {
        float4 b = ((const float4*)bias)[l32];
        ax = fmaxf(ax + b.x, 0.f); ay = fmaxf(ay + b.y, 0.f);
        az = fmaxf(az + b.z, 0.f); aw = fmaxf(aw + b.w, 0.f);
        ((float4*)outf)[(size_t)node * 32 + l32] = make_float4(ax, ay, az, aw);
    } else {
        ushort h0 = f2bf(ax), h1 = f2bf(ay), h2 = f2bf(az), h3 = f2bf(aw);
        uint2 hv = make_uint2((unsigned)h0 | ((unsigned)h1 << 16),
                              (unsigned)h2 | ((unsigned)h3 << 16));
        ushort l0 = f2bf(ax - bf2f(h0)), l1 = f2bf(ay - bf2f(h1));
        ushort l2 = f2bf(az - bf2f(h2)), l3 = f2bf(aw - bf2f(h3));
        uint2 lv = make_uint2((unsigned)l0 | ((unsigned)l1 << 16),
                              (unsigned)l2 | ((unsigned)l3 << 16));
        ((uint2*)outh)[(size_t)node * 32 + l32] = hv;
        ((uint2*)outl)[(size_t)node * 32 + l32] = lv;
    }
}

// --------------------- fused node GEMMs (layer1 + layer2) -------------------
__global__ __launch_bounds__(512) void gcn_mid_kernel(
        const ushort* __restrict__ Ah, const ushort* __restrict__ Al,   // y [Mpad][128]
        const ushort* __restrict__ B1h, const ushort* __restrict__ B1l, // W1t [256][128]
        const ushort* __restrict__ B2h, const ushort* __restrict__ B2l, // W2t [128][256]
        const float* __restrict__ bias1, const float* __restrict__ dinv,
        float* __restrict__ outf, int M) {
    __shared__ __align__(16) ushort t1f[2 * 128 * 256 + 2 * 128 * 32];  // 144 KB
    const int tid = threadIdx.x;
    const int w = tid >> 6, lane = tid & 63;
    const int bm = blockIdx.x * 128;
    const int sq = lane >> 4, r16 = lane & 15;

    // ---------------- stage 1: 2x4 wave grid, wave tile 64x64
    {
        const int wr = w >> 2, wc = w & 3;
        f32x4 acc1[4][4];
#pragma unroll
        for (int i = 0; i < 4; ++i)
#pragma unroll
            for (int j = 0; j < 4; ++j) acc1[i][j] = (f32x4)0.f;

        for (int kk = 0; kk < 128; kk += 32) {
            {
                int rowi = w * 16 + (lane >> 2);
                int u = lane & 3;
                int colk = kk + 8 * (u ^ SWZ(rowi));
                gload16(Ah + (size_t)(bm + rowi) * 128 + colk, t1f + w * 512);
                gload16(Al + (size_t)(bm + rowi) * 128 + colk, t1f + 4096 + w * 512);
            }
#pragma unroll
            for (int v = 0; v < 2; ++v) {
                int chunk = v * 8 + w;
                int rowi = chunk * 16 + (lane >> 2);
                int u = lane & 3;
                int colk = kk + 8 * (u ^ SWZ(rowi));
                gload16(B1h + (size_t)rowi * 128 + colk, t1f + 8192 + chunk * 512);
                gload16(B1l + (size_t)rowi * 128 + colk, t1f + 16384 + chunk * 512);
            }
            __syncthreads();

            bf16x8 ah[4], al[4], bh[4], bl[4];
#pragma unroll
            for (int f = 0; f < 4; ++f) {
                int ra = wr * 64 + f * 16 + r16;
                int oa = ra * 32 + 8 * (sq ^ SWZ(ra));
                ah[f] = *(const bf16x8*)(t1f + oa);
                al[f] = *(const bf16x8*)(t1f + 4096 + oa);
                int rb = wc * 64 + f * 16 + r16;
                int ob = rb * 32 + 8 * (sq ^ SWZ(rb));
                bh[f] = *(const bf16x8*)(t1f + 8192 + ob);
                bl[f] = *(const bf16x8*)(t1f + 16384 + ob);
            }
#pragma unroll
            for (int i = 0; i < 4; ++i)
#pragma unroll
                for (int j = 0; j < 4; ++j) {
                    acc1[i][j] = __builtin_amdgcn_mfma_f32_16x16x32_bf16(ah[i], bh[j], acc1[i][j], 0, 0, 0);
                    acc1[i][j] = __builtin_amdgcn_mfma_f32_16x16x32_bf16(ah[i], bl[j], acc1[i][j], 0, 0, 0);
                    acc1[i][j] = __builtin_amdgcn_mfma_f32_16x16x32_bf16(al[i], bh[j], acc1[i][j], 0, 0, 0);
                }
            __syncthreads();
        }

        const int q4 = lane >> 4;
#pragma unroll
        for (int j = 0; j < 4; ++j) {
            int col = wc * 64 + j * 16 + r16;
            float bv = bias1[col];
            int cslot = col >> 3, coff = col & 7;
#pragma unroll
            for (int i = 0; i < 4; ++i) {
                int rowb = wr * 64 + i * 16 + q4 * 4;
#pragma unroll
                for (int r = 0; r < 4; ++r) {
                    int rowt = rowb + r;
                    float v = fmaxf(acc1[i][j][r] + bv, 0.f);
                    ushort h = f2bf(v);
                    ushort lo = f2bf(v - bf2f(h));
                    int a = rowt * 256 + (((cslot ^ (rowt & 7)) << 3) + coff);
                    t1f[a] = h;
                    t1f[32768 + a] = lo;
                }
            }
        }
    }

    // ---------------- stage 2: 4x2 wave grid, wave tile 32x64, K=256
    {
        const int wr2 = w >> 1, wc2 = w & 1;
        const int q4 = lane >> 4;
        f32x4 acc2[2][4];
#pragma unroll
        for (int i = 0; i < 2; ++i)
#pragma unroll
            for (int j = 0; j < 4; ++j) acc2[i][j] = (f32x4)0.f;

        for (int kk = 0; kk < 256; kk += 32) {
            {
                int rowi = w * 16 + (lane >> 2);
                int u = lane & 3;
                int colk = kk + 8 * (u ^ SWZ(rowi));
                gload16(B2h + (size_t)rowi * 256 + colk, t1f + 65536 + w * 512);
                gload16(B2l + (size_t)rowi * 256 + colk, t1f + 69632 + w * 512);
            }
            __syncthreads();

            bf16x8 a2h[2], a2l[2], b2h[4], b2l[4];
#pragma unroll
            for (int f = 0; f < 2; ++f) {
                int ra = wr2 * 32 + f * 16 + r16;
                int k0 = kk + sq * 8;
                int ao = ra * 256 + (((k0 >> 3) ^ (ra & 7)) << 3);
                a2h[f] = *(const bf16x8*)(t1f + ao);
                a2l[f] = *(const bf16x8*)(t1f + 32768 + ao);
            }
#pragma unroll
            for (int f = 0; f < 4; ++f) {
                int rb = wc2 * 64 + f * 16 + r16;
                int ob = rb * 32 + 8 * (sq ^ SWZ(rb));
                b2h[f] = *(const bf16x8*)(t1f + 65536 + ob);
                b2l[f] = *(const bf16x8*)(t1f + 69632 + ob);
            }
#pragma unroll
            for (int i = 0; i < 2; ++i)
#pragma unroll
                for (int j = 0; j < 4; ++j) {
                    acc2[i][j] = __builtin_amdgcn_mfma_f32_16x16x32_bf16(a2h[i], b2h[j], acc2[i][j], 0, 0, 0);
                    acc2[i][j] = __builtin_amdgcn_mfma_f32_16x16x32_bf16(a2h[i], b2l[j], acc2[i][j], 0, 0, 0);
                    acc2[i][j] = __builtin_amdgcn_mfma_f32_16x16x32_bf16(a2l[i], b2h[j], acc2[i][j], 0, 0, 0);
                }
            __syncthreads();
        }

#pragma unroll
        for (int i = 0; i < 2; ++i) {
            int row0 = bm + wr2 * 32 + i * 16 + q4 * 4;
            if (row0 >= M) continue;
#pragma unroll
            for (int j = 0; j < 4; ++j) {
                int col = wc2 * 64 + j * 16 + r16;
#pragma unroll
                for (int r = 0; r < 4; ++r)
                    outf[(size_t)(row0 + r) * 128 + col] = acc2[i][j][r] * dinv[row0 + r];
            }
        }
    }
}

// ------------------------------- pooling -----------------------------------
__global__ void pool_kernel(const float* __restrict__ feats, const int* __restrict__ batch,
                            ushort* __restrict__ gh, ushort* __restrict__ gl, int N) {
    __shared__ float sm[256];
    int gid = blockIdx.x;
    int lo = 0, hi = N;
    while (lo < hi) { int m = (lo + hi) >> 1; if (batch[m] < gid) lo = m + 1; else hi = m; }
    int start = lo;
    lo = start; hi = N;
    while (lo < hi) { int m = (lo + hi) >> 1; if (batch[m] < gid + 1) lo = m + 1; else hi = m; }
    int end = lo;
    int tid = threadIdx.x;
    int f = tid & 127, half = tid >> 7;
    float acc = 0.f;
    for (int i = start + half; i < end; i += 2) acc += feats[(size_t)i * 128 + f];
    sm[tid] = acc;
    __syncthreads();
    if (half == 0) {
        acc += sm[tid + 128];
        int cnt = end - start; if (cnt < 1) cnt = 1;
        float m = acc / (float)cnt;
        ushort h = f2bf(m);
        gh[gid * 128 + f] = h;
        gl[gid * 128 + f] = f2bf(m - bf2f(h));
    }
}

// --------------------- fused MLP (cooperative, 64 blocks) -------------------
struct MLPArgs {
    const ushort *gh, *gl;
    const ushort *T1h, *T1l, *T2h, *T2l, *T22h, *T22l, *T23h, *T23l, *T3h, *T3l;
    const float *b1, *b2, *b22, *b23, *b3;
    ushort *a1h, *a1l, *a2h, *a2l, *a3h, *a3l, *a4h, *a4l;
    float *outp;
};

// one 64x64 tile set per block per layer; tile = 4 waves (2x2), 32x32/wave
__device__ __forceinline__ void mlp_layer(
        const ushort* __restrict__ Ah, const ushort* __restrict__ Al,
        const ushort* __restrict__ Bh, const ushort* __restrict__ Bl,
        const float* __restrict__ bias,
        ushort* __restrict__ Ch, ushort* __restrict__ Cl, float* __restrict__ Cf,
        int NN, int K, ushort* lds) {
    const int tid = threadIdx.x;
    const int w = tid >> 6, lane = tid & 63;
    const int wr = w >> 1, wc = w & 1;
    const int sq = lane >> 4, r16 = lane & 15;
    const int q4 = lane >> 4;
    int tiles = 4 * (NN >> 6);
    for (int t = blockIdx.x; t < tiles; t += gridDim.x) {
        int bm = (t & 3) << 6, bn = (t >> 2) << 6;
        const ushort* srcs[4] = {
            Ah + (size_t)bm * K, Al + (size_t)bm * K,
            Bh + (size_t)bn * K, Bl + (size_t)bn * K };
        f32x4 acc[2][2];
        acc[0][0] = acc[0][1] = acc[1][0] = acc[1][1] = (f32x4)0.f;
        for (int kk = 0; kk < K; kk += 32) {
            int rowi = w * 16 + (lane >> 2);
            int u = lane & 3;
            int colk = kk + 8 * (u ^ SWZ(rowi));
#pragma unroll
            for (int tpl = 0; tpl < 4; ++tpl)
                gload16(srcs[tpl] + (size_t)rowi * K + colk, lds + tpl * 2048 + w * 512);
            __syncthreads();
            bf16x8 ah[2], al2[2], bh2[2], bl2[2];
#pragma unroll
            for (int f = 0; f < 2; ++f) {
                int ra = wr * 32 + f * 16 + r16;
                int oa = ra * 32 + 8 * (sq ^ SWZ(ra));
                ah[f]  = *(const bf16x8*)(lds + oa);
                al2[f] = *(const bf16x8*)(lds + 2048 + oa);
                int rb = wc * 32 + f * 16 + r16;
                int ob = rb * 32 + 8 * (sq ^ SWZ(rb));
                bh2[f] = *(const bf16x8*)(lds + 4096 + ob);
                bl2[f] = *(const bf16x8*)(lds + 6144 + ob);
            }
#pragma unroll
            for (int i = 0; i < 2; ++i)
#pragma unroll
                for (int j = 0; j < 2; ++j) {
                    acc[i][j] = __builtin_amdgcn_mfma_f32_16x16x32_bf16(ah[i], bh2[j], acc[i][j], 0, 0, 0);
                    acc[i][j] = __builtin_amdgcn_mfma_f32_16x16x32_bf16(ah[i], bl2[j], acc[i][j], 0, 0, 0);
                    acc[i][j] = __builtin_amdgcn_mfma_f32_16x16x32_bf16(al2[i], bh2[j], acc[i][j], 0, 0, 0);
                }
            __syncthreads();
        }
#pragma unroll
        for (int i = 0; i < 2; ++i) {
            int row0 = bm + wr * 32 + i * 16 + q4 * 4;
#pragma unroll
            for (int j = 0; j < 2; ++j) {
                int colc = bn + wc * 32 + j * 16 + r16;
                float bv = bias[colc];
                if (Cf) {
#pragma unroll
                    for (int r = 0; r < 4; ++r)
                        Cf[(size_t)(row0 + r) * NN + colc] = acc[i][j][r] + bv;
                } else {
#pragma unroll
                    for (int r = 0; r < 4; ++r) {
                        float v = fmaxf(acc[i][j][r] + bv, 0.f);
                        ushort h = f2bf(v);
                        size_t o = (size_t)(row0 + r) * NN + colc;
                        Ch[o] = h;
                        Cl[o] = f2bf(v - bf2f(h));
                    }
                }
            }
        }
    }
}

__global__ __launch_bounds__(256) void mlp_fused_kernel(MLPArgs p) {
    __shared__ __align__(16) ushort lds[8192];   // 16 KB: 4 planes x 64 rows x 32
    cg::grid_group grid = cg::this_grid();
    mlp_layer(p.gh,  p.gl,  p.T1h,  p.T1l,  p.b1,  p.a1h, p.a1l, nullptr, 128,  128,  lds);
    __threadfence(); grid.sync();
    mlp_layer(p.a1h, p.a1l, p.T2h,  p.T2l,  p.b2,  p.a2h, p.a2l, nullptr, 1024, 128,  lds);
    __threadfence(); grid.sync();
    mlp_layer(p.a2h, p.a2l, p.T22h, p.T22l, p.b22, p.a3h, p.a3l, nullptr, 1024, 1024, lds);
    __threadfence(); grid.sync();
    mlp_layer(p.a3h, p.a3l, p.T23h, p.T23l, p.b23, p.a4h, p.a4l, nullptr, 1024, 1024, lds);
    __threadfence(); grid.sync();
    mlp_layer(p.a4h, p.a4l, p.T3h,  p.T3l,  p.b3,  nullptr, nullptr, p.outp, 128, 1024, lds);
}

// ---------------------------------------------------------------------------

extern "C" void kernel_launch(void* const* d_in, const int* in_sizes, int n_in,
                              void* d_out, int out_size, void* d_ws, size_t ws_size,
                              hipStream_t stream) {
    const float* x    = (const float*)d_in[0];
    const int*   ei   = (const int*)d_in[1];
    const int*   batch= (const int*)d_in[2];
    const float* W1   = (const float*)d_in[3];
    const float* b1   = (const float*)d_in[4];
    const float* W2   = (const float*)d_in[5];
    const float* b2   = (const float*)d_in[6];
    const float* Wl1  = (const float*)d_in[7];
    const float* bl1  = (const float*)d_in[8];
    const float* Wl2  = (const float*)d_in[9];
    const float* bl2  = (const float*)d_in[10];
    const float* Wl22 = (const float*)d_in[11];
    const float* bl22 = (const float*)d_in[12];
    const float* Wl23 = (const float*)d_in[13];
    const float* bl23 = (const float*)d_in[14];
    const float* Wl3  = (const float*)d_in[15];
    const float* bl3  = (const float*)d_in[16];

    const int D = 128;
    const int N = in_sizes[0] / D;            // 50000
    const int E = in_sizes[1] / 2;            // 800000
    const int G = out_size / D;               // 256
    const int H = in_sizes[10];               // 1024
    const int Mpad = ((N + 127) / 128) * 128; // 50048
    const int* row = ei;
    const int* col = ei + E;
    float* out = (float*)d_out;

    char* ws = (char*)d_ws;
    auto alloc = [&](size_t bytes) -> void* {
        void* p = (void*)ws;
        ws += (bytes + 255) & ~(size_t)255;
        return p;
    };
    int*    indeg  = (int*)alloc((size_t)N * 4);
    int*    cursor = (int*)alloc((size_t)N * 4);
    int*    offs   = (int*)alloc((size_t)(N + 1) * 4);
    int*    adj    = (int*)alloc((size_t)E * 4);
    float*  dinv   = (float*)alloc((size_t)N * 4);
    int*    bsum   = (int*)alloc((size_t)1024 * 4);
    ushort* W1th   = (ushort*)alloc((size_t)256 * 128 * 2);
    ushort* W1tl   = (ushort*)alloc((size_t)256 * 128 * 2);
    ushort* W2th   = (ushort*)alloc((size_t)128 * 256 * 2);
    ushort* W2tl   = (ushort*)alloc((size_t)128 * 256 * 2);
    ushort* Tl1h  = (ushort*)alloc((size_t)128 * 128 * 2);
    ushort* Tl1l  = (ushort*)alloc((size_t)128 * 128 * 2);
    ushort* Tl2h  = (ushort*)alloc((size_t)H * 128 * 2);
    ushort* Tl2l  = (ushort*)alloc((size_t)H * 128 * 2);
    ushort* Tl22h = (ushort*)alloc((size_t)H * H * 2);
    ushort* Tl22l = (ushort*)alloc((size_t)H * H * 2);
    ushort* Tl23h = (ushort*)alloc((size_t)H * H * 2);
    ushort* Tl23l = (ushort*)alloc((size_t)H * H * 2);
    ushort* Tl3h  = (ushort*)alloc((size_t)128 * H * 2);
    ushort* Tl3l  = (ushort*)alloc((size_t)128 * H * 2);
    ushort* yh     = (ushort*)alloc((size_t)Mpad * 128 * 2);
    ushort* yl     = (ushort*)alloc((size_t)Mpad * 128 * 2);
    float*  hs2    = (float*)alloc((size_t)Mpad * 128 * 4);
    float*  yf     = (float*)alloc((size_t)Mpad * 128 * 4);
    ushort* gh     = (ushort*)alloc((size_t)G * 128 * 2);
    ushort* gl     = (ushort*)alloc((size_t)G * 128 * 2);
    ushort* a1h    = (ushort*)alloc((size_t)G * 128 * 2);
    ushort* a1l    = (ushort*)alloc((size_t)G * 128 * 2);
    ushort* a2h    = (ushort*)alloc((size_t)G * H * 2);
    ushort* a2l    = (ushort*)alloc((size_t)G * H * 2);
    ushort* a3h    = (ushort*)alloc((size_t)G * H * 2);
    ushort* a3l    = (ushort*)alloc((size_t)G * H * 2);
    ushort* a4h    = (ushort*)alloc((size_t)G * H * 2);
    ushort* a4l    = (ushort*)alloc((size_t)G * H * 2);

    // ---- CSR build + normalization ----
    hipMemsetAsync(indeg, 0, (size_t)N * 4, stream);
    count_deg_kernel<<<(E + 255) / 256, 256, 0, stream>>>(col, E, indeg);
    {
        int nb = (N + 1023) / 1024;   // 49
        scan_p1_kernel<<<nb, 256, 0, stream>>>(indeg, bsum, N);
        scan_p2_kernel<<<1, 1024, 0, stream>>>(bsum, nb);
        scan_p3_kernel<<<nb, 256, 0, stream>>>(indeg, bsum, offs, dinv, N);
    }
    hipMemcpyAsync(cursor, offs, (size_t)N * 4, hipMemcpyDeviceToDevice, stream);
    fill_adj_kernel<<<(E + 255) / 256, 256, 0, stream>>>(row, col, cursor, adj, E);

    // ---- weight transpose + split (single fused launch) ----
    {
        TJobs jb;
        const float* Ws[7]  = {W1, W2, Wl1, Wl2, Wl22, Wl23, Wl3};
        ushort* Ths[7]      = {W1th, W2th, Tl1h, Tl2h, Tl22h, Tl23h, Tl3h};
        ushort* Tls[7]      = {W1tl, W2tl, Tl1l, Tl2l, Tl22l, Tl23l, Tl3l};
        int Ks[7]           = {128, 256, 128, 128, H, H, H};
        int Nns[7]          = {256, 128, 128, H, H, H, 128};
        int off = 0;
        for (int j = 0; j < 7; ++j) {
            jb.W[j] = Ws[j]; jb.Th[j] = Ths[j]; jb.Tl[j] = Tls[j];
            jb.K[j] = Ks[j]; jb.Nn[j] = Nns[j];
            jb.off[j] = off;
            off += (Ks[j] / 64) * (Nns[j] / 64);
        }
        jb.off[7] = off;
        tsplit_all_kernel<<<off, 256, 0, stream>>>(jb);
    }

    // ---- Layer 1 aggregate (dinv folded) -> bf16 split ----
    aggregate128_kernel<1><<<(N + 7) / 8, 256, 0, stream>>>(
        x, offs, adj, dinv, nullptr, nullptr, yh, yl, N);

    // ---- fused node GEMMs: hs2 = dinv * (relu(y@W1+b1) @ W2) ----
    gcn_mid_kernel<<<Mpad / 128, 512, 0, stream>>>(
        yh, yl, W1th, W1tl, W2th, W2tl, b1, dinv, hs2, N);

    // ---- Layer 2 aggregate + b2 + relu ----
    aggregate128_kernel<0><<<(N + 7) / 8, 256, 0, stream>>>(
        hs2, offs, adj, dinv, b2, yf, nullptr, nullptr, N);

    // ---- global mean pool (emits bf16 hi/lo) ----
    pool_kernel<<<G, 256, 0, stream>>>(yf, batch, gh, gl, N);

    // ---- fused MLP: one cooperative dispatch, grid.sync between layers ----
    {
        MLPArgs ma;
        ma.gh = gh; ma.gl = gl;
        ma.T1h = Tl1h;  ma.T1l = Tl1l;
        ma.T2h = Tl2h;  ma.T2l = Tl2l;
        ma.T22h = Tl22h; ma.T22l = Tl22l;
        ma.T23h = Tl23h; ma.T23l = Tl23l;
        ma.T3h = Tl3h;  ma.T3l = Tl3l;
        ma.b1 = bl1; ma.b2 = bl2; ma.b22 = bl22; ma.b23 = bl23; ma.b3 = bl3;
        ma.a1h = a1h; ma.a1l = a1l;
        ma.a2h = a2h; ma.a2l = a2l;
        ma.a3h = a3h; ma.a3l = a3l;
        ma.a4h = a4h; ma.a4l = a4l;
        ma.outp = out;
        void* kargs[] = { &ma };
        hipLaunchCooperativeKernel((void*)mlp_fused_kernel, dim3(64), dim3(256),
                                   kargs, 0, stream);
    }
}